// Round 5
// baseline (9400.382 us; speedup 1.0000x reference)
//
#include <hip/hip_runtime.h>
#include <math.h>

// Problem constants
constexpr int B  = 128;
constexpr int T  = 512;
constexpr int IN = 32;
constexpr int H  = 256;
constexpr int D  = 2 * H;     // 512
constexpr int NC = 1024;      // codebook entries

// cooperative GRU geometry
constexpr int NG   = 64;      // groups (32 fwd + 32 bwd)
constexpr int GW   = 4;       // WGs per group
constexpr int SEQ  = 4;       // sequences per group
constexpr int NTHR = 768;     // 8 k-chunks x 96 row-pairs

// ---------------------------------------------------------------------------
// prep kernels
// ---------------------------------------------------------------------------

__global__ void k_zero(int* __restrict__ counts, double* __restrict__ lsum) {
    const int i = blockIdx.x * 256 + threadIdx.x;
    if (i < NC) counts[i] = 0;
    if (i == 0) *lsum = 0.0;
}

__global__ void k_lengths(const int* __restrict__ mask, int* __restrict__ last) {
    const int b = blockIdx.x;
    const int t = threadIdx.x;   // 64 threads = 1 wave
    int s = 0;
    #pragma unroll
    for (int m = 0; m < T / 64; ++m) s += mask[b * T + m * 64 + t];
    #pragma unroll
    for (int off = 32; off > 0; off >>= 1) s += __shfl_down(s, off, 64);
    if (t == 0) last[b] = s - 1;
}

// build direction-pure, length-sorted groups of 4 tasks
__global__ void k_plan(const int* __restrict__ last, int* __restrict__ plan,
                       int* __restrict__ slen, int* __restrict__ glen) {
    __shared__ int ll[B];
    const int t = threadIdx.x;   // 128
    ll[t] = last[t];
    __syncthreads();
    const int lf = ll[t] + 1;       // fwd steps
    const int lb = T - ll[t];       // bwd steps
    int rf = 0, rb = 0;
    for (int j = 0; j < B; ++j) {
        const int ljf = ll[j] + 1, ljb = T - ll[j];
        rf += (ljf > lf) || (ljf == lf && j < t);   // descending
        rb += (ljb > lb) || (ljb == lb && j < t);
    }
    plan[rf] = t;       slen[rf] = lf;
    plan[128 + rb] = t; slen[128 + rb] = lb;
    if ((rf & 3) == 0) glen[rf >> 2] = lf;          // rank 4g = group max
    if ((rb & 3) == 0) glen[32 + (rb >> 2)] = lb;
}

// transpose codebook for k_vq
__global__ void k_transpose(float* __restrict__ dst, const float* __restrict__ src,
                            int rows, int cols) {
    const int idx = blockIdx.x * 256 + threadIdx.x;
    const int r = idx % rows;
    const int c = idx / rows;
    dst[idx] = src[r * cols + c];
}

__global__ void k_cbn2(const float* __restrict__ cb, double* __restrict__ cbn2) {
    const int c = blockIdx.x * 256 + threadIdx.x;
    double s = 0.0;
    for (int k = 0; k < D; ++k) {
        const double e = (double)cb[c * D + k];
        s += e * e;
    }
    cbn2[c] = s;
}

// ---------------------------------------------------------------------------
// Cooperative GRU. Per-thread decomposition: 2 rows x 32 k x 4 seqs.
// Weights in VGPRs; x-dot merged into r/z partials; n-gate x kept separate.
// 4 WGs/group exchange h as step-tagged 8B words through the LLC.
// ---------------------------------------------------------------------------

__device__ __forceinline__ float sigmoidf_(float x) {
    return 1.0f / (1.0f + expf(-x));
}

__global__ __launch_bounds__(NTHR, 3) void k_gru(
    const float* __restrict__ traj,
    const float* __restrict__ Whf, const float* __restrict__ Whb,
    const float* __restrict__ Wxf, const float* __restrict__ Wxb,
    const float* __restrict__ bxf, const float* __restrict__ bhf,
    const float* __restrict__ bxb, const float* __restrict__ bhb,
    const int* __restrict__ plan, const int* __restrict__ slen,
    const int* __restrict__ glen,
    unsigned long long* __restrict__ hgt,  // [2][NG][GW][SEQ*64] tagged pairs
    float* __restrict__ ze)                // [B][512]
{
    const int g   = blockIdx.x & 63;     // same-XCD members under %8 round-robin
    const int w   = blockIdx.x >> 6;
    const int dir = (g >= 32) ? 1 : 0;

    const float* __restrict__ Wh = dir ? Whb : Whf;
    const float* __restrict__ Wx = dir ? Wxb : Wxf;
    const float* __restrict__ bx = dir ? bxb : bxf;
    const float* __restrict__ bh = dir ? bhb : bhf;

    const int tid = threadIdx.x;
    const int kq  = tid / 96;            // k-chunk 0..7 (<=2 per wave)
    const int rp  = tid - kq * 96;       // row-pair 0..95
    const int lr0 = 2 * rp;              // local gate-rows lr0, lr0+1
    const int gi  = lr0 >> 6;            // gate 0=r,1=z,2=n (same for both rows)
    const int Rg0 = gi * H + w * 64 + (lr0 & 63);   // global gate-row of lr0
    const bool is_n = (gi == 2);

    __shared__ float4 h4[SEQ][64];            // full h per sequence (4 KB)
    __shared__ float  P[8][SEQ][194];         // merged partials [kq][s][row]
    __shared__ float  Pnx[8][SEQ][66];        // n-gate x partials [kq][s][j]
    __shared__ float4 xb4[2][SEQ][8];         // x_t ping-pong
    __shared__ int    bbS[SEQ], lsS[SEQ];

    if (tid < SEQ) { bbS[tid] = plan[g * 4 + tid]; lsS[tid] = slen[g * 4 + tid]; }
    {   // zero h
        float2* hp = (float2*)h4;
        if (tid < 512) hp[tid] = make_float2(0.0f, 0.0f);
    }
    const int L = glen[g];

    // one-time weight load into registers: 2 rows x 32 k
    float4 wh0[8], wh1[8];
    {
        const float4* p0 = (const float4*)(Wh + (size_t)Rg0 * 256 + kq * 32);
        const float4* p1 = (const float4*)(Wh + (size_t)(Rg0 + 1) * 256 + kq * 32);
        #pragma unroll
        for (int i = 0; i < 8; ++i) { wh0[i] = p0[i]; wh1[i] = p1[i]; }
    }
    const float4 wx0 = *(const float4*)(Wx + Rg0 * 32 + kq * 4);
    const float4 wx1 = *(const float4*)(Wx + (Rg0 + 1) * 32 + kq * 4);

    // biases for gate threads (tid<256) in registers
    float bxr = 0, bxz = 0, bxn = 0, bhr = 0, bhz = 0, bhn = 0;
    if (tid < 256) {
        const int j2 = tid & 63;
        bxr = bx[w * 64 + j2]; bxz = bx[H + w * 64 + j2]; bxn = bx[2 * H + w * 64 + j2];
        bhr = bh[w * 64 + j2]; bhz = bh[H + w * 64 + j2]; bhn = bh[2 * H + w * 64 + j2];
    }
    __syncthreads();
    // x for step 1
    if (tid < 128) {
        const int s = tid >> 5, i = tid & 31;
        const int t0 = dir ? (T - 1) : 0;
        ((float*)xb4)[128 + s * 32 + i] = traj[(bbS[s] * T + t0) * IN + i];
    }
    __syncthreads();

    const int u = tid - 256;             // gather-thread index

    for (int step = 1; step <= L; ++step) {
        const int buf = step & 1;
        unsigned long long* __restrict__ slab =
            hgt + (buf * NG + g) * (GW * SEQ * 64);

        // ---- phase 1: partial dot products (weights in VGPRs) ----
        float a[2][4];
        #pragma unroll
        for (int s = 0; s < 4; ++s) { a[0][s] = 0.0f; a[1][s] = 0.0f; }
        #pragma unroll
        for (int i = 0; i < 8; ++i) {
            const float4 w0 = wh0[i], w1 = wh1[i];
            #pragma unroll
            for (int s = 0; s < 4; ++s) {
                const float4 hv = h4[s][kq * 8 + i];
                a[0][s] = fmaf(w0.x, hv.x, fmaf(w0.y, hv.y,
                          fmaf(w0.z, hv.z, fmaf(w0.w, hv.w, a[0][s]))));
                a[1][s] = fmaf(w1.x, hv.x, fmaf(w1.y, hv.y,
                          fmaf(w1.z, hv.z, fmaf(w1.w, hv.w, a[1][s]))));
            }
        }
        float nx0[4], nx1[4];
        #pragma unroll
        for (int s = 0; s < 4; ++s) {
            const float4 xv = xb4[buf][s][kq];
            if (!is_n) {
                a[0][s] = fmaf(wx0.x, xv.x, fmaf(wx0.y, xv.y,
                          fmaf(wx0.z, xv.z, fmaf(wx0.w, xv.w, a[0][s]))));
                a[1][s] = fmaf(wx1.x, xv.x, fmaf(wx1.y, xv.y,
                          fmaf(wx1.z, xv.z, fmaf(wx1.w, xv.w, a[1][s]))));
            } else {
                nx0[s] = wx0.x * xv.x + wx0.y * xv.y + wx0.z * xv.z + wx0.w * xv.w;
                nx1[s] = wx1.x * xv.x + wx1.y * xv.y + wx1.z * xv.z + wx1.w * xv.w;
            }
        }
        #pragma unroll
        for (int s = 0; s < 4; ++s) {
            float2 pv; pv.x = a[0][s]; pv.y = a[1][s];
            *(float2*)&P[kq][s][lr0] = pv;
            if (is_n) {
                float2 pz; pz.x = nx0[s]; pz.y = nx1[s];
                *(float2*)&Pnx[kq][s][lr0 - 128] = pz;
            }
        }
        __syncthreads();

        // ---- phase 2 (tid<256): gates + publish; (tid>=256): gather + x ----
        if (tid < 256) {
            const int j2 = tid & 63, s = tid >> 6;
            float hr = 0.f, hz = 0.f, hn_ = 0.f, xn = 0.f;
            #pragma unroll
            for (int kk = 0; kk < 8; ++kk) {
                hr  += P[kk][s][j2];
                hz  += P[kk][s][64 + j2];
                hn_ += P[kk][s][128 + j2];
                xn  += Pnx[kk][s][j2];
            }
            const float r = sigmoidf_(hr + bxr + bhr);      // x merged into hr
            const float z = sigmoidf_(hz + bxz + bhz);
            const float n = tanhf(xn + bxn + r * (hn_ + bhn));
            const int jg = w * 64 + j2;
            const float hp = ((const float*)h4)[s * 256 + jg];
            const float hnew = (1.0f - z) * n + z * hp;
            ((float*)h4)[s * 256 + jg] = hnew;
            union { float f; unsigned ui; } cv; cv.f = hnew;
            const unsigned long long pk =
                ((unsigned long long)(unsigned)step << 32) | cv.ui;
            __hip_atomic_store(&slab[w * 256 + s * 64 + j2], pk,
                               __ATOMIC_RELAXED, __HIP_MEMORY_SCOPE_AGENT);
            if (step == lsS[s]) ze[bbS[s] * D + dir * H + jg] = hnew;
        } else {
            // x prefetch (issue early; completes during spins)
            float xval = 0.0f;
            int xs = 0, xi = 0;
            const bool do_x = (u < 128) && (step < L);
            if (do_x) {
                xs = u >> 5; xi = u & 31;
                const int tn = dir ? (T - 1 - step) : step;
                xval = traj[(bbS[xs] * T + tn) * IN + xi];
            }
            const int p0 = u >> 8;               // peer-list index 0,1
            const int r2 = u & 255;
            const int s0 = r2 >> 6, j0 = r2 & 63;
            const int pw0 = p0 + (p0 >= w ? 1 : 0);
            unsigned long long* a0 = &slab[pw0 * 256 + s0 * 64 + j0];
            if (u < 256) {
                const int pw1 = 2 + (2 >= w ? 1 : 0);
                unsigned long long* a1 = &slab[pw1 * 256 + s0 * 64 + j0];
                unsigned long long v0 = 0, v1 = 0;
                bool d0 = false, d1 = false;
                do {   // concurrent double-poll: both loads in flight
                    if (!d0) { v0 = __hip_atomic_load(a0, __ATOMIC_RELAXED,
                                   __HIP_MEMORY_SCOPE_AGENT); d0 = ((int)(v0 >> 32) >= step); }
                    if (!d1) { v1 = __hip_atomic_load(a1, __ATOMIC_RELAXED,
                                   __HIP_MEMORY_SCOPE_AGENT); d1 = ((int)(v1 >> 32) >= step); }
                } while (!(d0 && d1));
                union { unsigned ui; float f; } c0, c1;
                c0.ui = (unsigned)v0; c1.ui = (unsigned)v1;
                ((float*)h4)[s0 * 256 + pw0 * 64 + j0] = c0.f;
                ((float*)h4)[s0 * 256 + pw1 * 64 + j0] = c1.f;
            } else {
                unsigned long long v0;
                do {
                    v0 = __hip_atomic_load(a0, __ATOMIC_RELAXED,
                                           __HIP_MEMORY_SCOPE_AGENT);
                } while ((int)(v0 >> 32) < step);
                union { unsigned ui; float f; } c0; c0.ui = (unsigned)v0;
                ((float*)h4)[s0 * 256 + pw0 * 64 + j0] = c0.f;
            }
            if (do_x)
                ((float*)xb4)[(buf ^ 1) * 128 + xs * 32 + xi] = xval;
        }
        __syncthreads();
    }
}

// ---------------------------------------------------------------------------
// VQ: fp64 distance accumulation to match the numpy (fp64) argmin ordering.
// ---------------------------------------------------------------------------

__global__ __launch_bounds__(256) void k_vq(
    const float* __restrict__ ze, const float* __restrict__ cbT,
    const float* __restrict__ cb, const double* __restrict__ cbn2,
    int* __restrict__ counts, double* __restrict__ lsum,
    float* __restrict__ out)
{
    __shared__ float lz[D];
    __shared__ double ds[256];
    __shared__ int cs[256];

    const int b = blockIdx.x;
    const int t = threadIdx.x;

    lz[t]       = ze[b * D + t];
    lz[t + 256] = ze[b * D + 256 + t];
    __syncthreads();

    double best = 1e300;
    int bc = 0;
    for (int m = 0; m < NC / 256; ++m) {
        const int c = m * 256 + t;
        double s2 = 0.0;
        #pragma unroll 4
        for (int k = 0; k < D; ++k)
            s2 += (double)lz[k] * (double)cbT[k * NC + c];
        const double dist = cbn2[c] - 2.0 * s2;
        if (dist < best) { best = dist; bc = c; }
    }
    ds[t] = best; cs[t] = bc;
    __syncthreads();
    for (int s = 128; s > 0; s >>= 1) {
        if (t < s) {
            if (ds[t + s] < ds[t] || (ds[t + s] == ds[t] && cs[t + s] < cs[t])) {
                ds[t] = ds[t + s]; cs[t] = cs[t + s];
            }
        }
        __syncthreads();
    }
    const int idx = cs[0];
    __syncthreads();

    if (t == 0) atomicAdd(&counts[idx], 1);

    double loc = 0.0;
    for (int jj = t; jj < D; jj += 256) {
        const float zev = lz[jj];
        const float zqv = cb[idx * D + jj];
        out[b * D + jj] = zev + (zqv - zev);
        const double df = (double)zqv - (double)zev;
        loc += df * df;
    }
    ds[t] = loc;
    __syncthreads();
    for (int s = 128; s > 0; s >>= 1) {
        if (t < s) ds[t] += ds[t + s];
        __syncthreads();
    }
    if (t == 0) atomicAdd(lsum, ds[0]);
}

__global__ void k_final(const int* __restrict__ counts,
                        const double* __restrict__ lsum,
                        float* __restrict__ out)
{
    __shared__ double ds[256];
    const int t = threadIdx.x;
    double s = 0.0;
    for (int c = t; c < NC; c += 256) {
        const double p = (double)counts[c] / (double)B;
        s += p * log(p + 1e-10);
    }
    ds[t] = s;
    __syncthreads();
    for (int r = 128; r > 0; r >>= 1) {
        if (t < r) ds[t] += ds[t + r];
        __syncthreads();
    }
    if (t == 0) {
        out[B * D]     = (float)(lsum[0] * 1.25 / (double)(B * D));
        out[B * D + 1] = (float)exp(-ds[0]);
    }
}

// ---------------------------------------------------------------------------
// launch
// ---------------------------------------------------------------------------

extern "C" void kernel_launch(void* const* d_in, const int* in_sizes, int n_in,
                              void* d_out, int out_size, void* d_ws, size_t ws_size,
                              hipStream_t stream) {
    const float* traj = (const float*)d_in[0];
    const int*   mask = (const int*)d_in[1];
    const float* Wxf  = (const float*)d_in[2];
    const float* Whf  = (const float*)d_in[3];
    const float* bxf  = (const float*)d_in[4];
    const float* bhf  = (const float*)d_in[5];
    const float* Wxb  = (const float*)d_in[6];
    const float* Whb  = (const float*)d_in[7];
    const float* bxb  = (const float*)d_in[8];
    const float* bhb  = (const float*)d_in[9];
    const float* cb   = (const float*)d_in[10];
    float* out = (float*)d_out;

    // workspace layout
    float* ws    = (float*)d_ws;
    float* cbT   = ws;                     // 512*1024 = 524288 floats
    float* zebuf = cbT + 524288;           // 128*512  = 65536
    unsigned long long* hgt =
        (unsigned long long*)(zebuf + 65536);   // 2*64*4*256 u64 = 131072 (1 MB)
    int*   last  = (int*)(hgt + 131072);   // 128
    int*   plan  = last + 128;             // 256
    int*   slen  = plan + 256;             // 256
    int*   glen  = slen + 256;             // 64
    int*   cnts  = glen + 64;              // 1024
    double* cbn2 = (double*)(cnts + 1024 + 4); // 1024 doubles (8B aligned)
    double* lsum = cbn2 + 1024;            // 1 double

    k_zero<<<dim3(4), dim3(256), 0, stream>>>(cnts, lsum);
    k_lengths<<<dim3(B), dim3(64), 0, stream>>>(mask, last);
    k_plan<<<dim3(1), dim3(B), 0, stream>>>(last, plan, slen, glen);

    k_transpose<<<dim3(2048), dim3(256), 0, stream>>>(cbT, cb, NC, D);
    k_cbn2<<<dim3(4), dim3(256), 0, stream>>>(cb, cbn2);

    k_gru<<<dim3(NG * GW), dim3(NTHR), 0, stream>>>(
        traj, Whf, Whb, Wxf, Wxb, bxf, bhf, bxb, bhb,
        plan, slen, glen, hgt, zebuf);

    k_vq<<<dim3(B), dim3(256), 0, stream>>>(zebuf, cbT, cb, cbn2, cnts, lsum, out);
    k_final<<<dim3(1), dim3(256), 0, stream>>>(cnts, lsum, out);
}

// Round 6
// 1678.777 us; speedup vs baseline: 5.5995x; 5.5995x over previous
//
#include <hip/hip_runtime.h>
#include <math.h>

// Problem constants
constexpr int B  = 128;
constexpr int T  = 512;
constexpr int IN = 32;
constexpr int H  = 256;
constexpr int D  = 2 * H;     // 512
constexpr int NC = 1024;      // codebook entries

// cooperative GRU geometry
constexpr int NG   = 64;      // groups (32 fwd + 32 bwd)
constexpr int GW   = 4;       // WGs per group
constexpr int SEQ  = 4;       // sequences per group
constexpr int NTHR = 768;     // 8 k-chunks x 96 row-pairs

// ---------------------------------------------------------------------------
// prep kernels
// ---------------------------------------------------------------------------

__global__ void k_zero(int* __restrict__ counts, double* __restrict__ lsum) {
    const int i = blockIdx.x * 256 + threadIdx.x;
    if (i < NC) counts[i] = 0;
    if (i == 0) *lsum = 0.0;
}

__global__ void k_lengths(const int* __restrict__ mask, int* __restrict__ last) {
    const int b = blockIdx.x;
    const int t = threadIdx.x;   // 64 threads = 1 wave
    int s = 0;
    #pragma unroll
    for (int m = 0; m < T / 64; ++m) s += mask[b * T + m * 64 + t];
    #pragma unroll
    for (int off = 32; off > 0; off >>= 1) s += __shfl_down(s, off, 64);
    if (t == 0) last[b] = s - 1;
}

// build direction-pure, length-sorted groups of 4 tasks
__global__ void k_plan(const int* __restrict__ last, int* __restrict__ plan,
                       int* __restrict__ slen, int* __restrict__ glen) {
    __shared__ int ll[B];
    const int t = threadIdx.x;   // 128
    ll[t] = last[t];
    __syncthreads();
    const int lf = ll[t] + 1;       // fwd steps
    const int lb = T - ll[t];       // bwd steps
    int rf = 0, rb = 0;
    for (int j = 0; j < B; ++j) {
        const int ljf = ll[j] + 1, ljb = T - ll[j];
        rf += (ljf > lf) || (ljf == lf && j < t);   // descending
        rb += (ljb > lb) || (ljb == lb && j < t);
    }
    plan[rf] = t;       slen[rf] = lf;
    plan[128 + rb] = t; slen[128 + rb] = lb;
    if ((rf & 3) == 0) glen[rf >> 2] = lf;          // rank 4g = group max
    if ((rb & 3) == 0) glen[32 + (rb >> 2)] = lb;
}

// transpose codebook for k_vq
__global__ void k_transpose(float* __restrict__ dst, const float* __restrict__ src,
                            int rows, int cols) {
    const int idx = blockIdx.x * 256 + threadIdx.x;
    const int r = idx % rows;
    const int c = idx / rows;
    dst[idx] = src[r * cols + c];
}

__global__ void k_cbn2(const float* __restrict__ cb, double* __restrict__ cbn2) {
    const int c = blockIdx.x * 256 + threadIdx.x;
    double s = 0.0;
    for (int k = 0; k < D; ++k) {
        const double e = (double)cb[c * D + k];
        s += e * e;
    }
    cbn2[c] = s;
}

// ---------------------------------------------------------------------------
// Cooperative GRU. Per-thread: 2 rows x 32 k x 4 seqs, but in the round-4
// allocator shape: ONE float4 wh[16] array (wh[i]=row lr0, wh[8+i]=row lr0+1),
// uniform unrolled loop, no divergence in phase 1, separate Px partials.
// 4 WGs/group exchange h as step-tagged 8B words through the LLC.
// ---------------------------------------------------------------------------

__device__ __forceinline__ float sigmoidf_(float x) {
    return 1.0f / (1.0f + expf(-x));
}

__global__ __launch_bounds__(NTHR, 3) void k_gru(
    const float* __restrict__ traj,
    const float* __restrict__ Whf, const float* __restrict__ Whb,
    const float* __restrict__ Wxf, const float* __restrict__ Wxb,
    const float* __restrict__ bxf, const float* __restrict__ bhf,
    const float* __restrict__ bxb, const float* __restrict__ bhb,
    const int* __restrict__ plan, const int* __restrict__ slen,
    const int* __restrict__ glen,
    unsigned long long* __restrict__ hgt,  // [2][NG][GW][SEQ*64] tagged pairs
    float* __restrict__ ze)                // [B][512]
{
    const int g   = blockIdx.x & 63;     // same-XCD members under %8 round-robin
    const int w   = blockIdx.x >> 6;
    const int dir = (g >= 32) ? 1 : 0;

    const float* __restrict__ Wh = dir ? Whb : Whf;
    const float* __restrict__ Wx = dir ? Wxb : Wxf;
    const float* __restrict__ bx = dir ? bxb : bxf;
    const float* __restrict__ bh = dir ? bhb : bhf;

    const int tid = threadIdx.x;
    const int kq  = tid / 96;            // k-chunk 0..7 (<=2 per wave)
    const int rp  = tid - kq * 96;       // row-pair 0..95
    const int lr0 = 2 * rp;              // local gate-rows lr0, lr0+1
    const int gi  = lr0 >> 6;            // gate 0=r,1=z,2=n (same both rows)
    const int Rg0 = gi * H + w * 64 + (lr0 & 63);   // global gate-row of lr0

    __shared__ float4 h4[SEQ][64];            // full h per sequence (4 KB)
    __shared__ float  P [8][SEQ][194];        // h-dot partials [kq][s][row]
    __shared__ float  Px[8][SEQ][194];        // x-dot partials [kq][s][row]
    __shared__ float4 xb4[2][SEQ][8];         // x_t ping-pong
    __shared__ int    bbS[SEQ], lsS[SEQ];

    if (tid < SEQ) { bbS[tid] = plan[g * 4 + tid]; lsS[tid] = slen[g * 4 + tid]; }
    {   // zero h
        float2* hp = (float2*)h4;
        if (tid < 512) hp[tid] = make_float2(0.0f, 0.0f);
    }
    const int L = glen[g];

    // one-time weight load into registers: single array, round-4 shape.
    // wh[0..7]  = row Rg0,   k = kq*32 .. kq*32+31
    // wh[8..15] = row Rg0+1, same k range
    float4 wh[16];
    {
        const float4* p0 = (const float4*)(Wh + (size_t)Rg0 * 256 + kq * 32);
        const float4* p1 = (const float4*)(Wh + (size_t)(Rg0 + 1) * 256 + kq * 32);
        #pragma unroll
        for (int i = 0; i < 8; ++i) { wh[i] = p0[i]; wh[8 + i] = p1[i]; }
    }
    const float4 wx0 = *(const float4*)(Wx + Rg0 * 32 + kq * 4);
    const float4 wx1 = *(const float4*)(Wx + (Rg0 + 1) * 32 + kq * 4);

    // biases for gate threads (tid<256) in registers
    float bxr = 0, bxz = 0, bxn = 0, bhr = 0, bhz = 0, bhn = 0;
    if (tid < 256) {
        const int j2 = tid & 63;
        bxr = bx[w * 64 + j2]; bxz = bx[H + w * 64 + j2]; bxn = bx[2 * H + w * 64 + j2];
        bhr = bh[w * 64 + j2]; bhz = bh[H + w * 64 + j2]; bhn = bh[2 * H + w * 64 + j2];
    }
    __syncthreads();
    // x for step 1
    if (tid < 128) {
        const int s = tid >> 5, i = tid & 31;
        const int t0 = dir ? (T - 1) : 0;
        ((float*)xb4)[128 + s * 32 + i] = traj[(bbS[s] * T + t0) * IN + i];
    }
    __syncthreads();

    const int u = tid - 256;             // gather-thread index

    for (int step = 1; step <= L; ++step) {
        const int buf = step & 1;
        unsigned long long* __restrict__ slab =
            hgt + (buf * NG + g) * (GW * SEQ * 64);

        // ---- phase 1: partial dot products (weights in VGPRs) ----
        float4 a0 = {0,0,0,0}, a1 = {0,0,0,0}, a2 = {0,0,0,0}, a3 = {0,0,0,0};
        float4 c0 = {0,0,0,0}, c1 = {0,0,0,0}, c2 = {0,0,0,0}, c3 = {0,0,0,0};
        #pragma unroll
        for (int i = 0; i < 8; ++i) {
            const float4 w0 = wh[i];
            const float4 w1 = wh[8 + i];
            float4 hv;
            hv = h4[0][kq * 8 + i];
            a0.x = fmaf(w0.x, hv.x, a0.x); a0.y = fmaf(w0.y, hv.y, a0.y);
            a0.z = fmaf(w0.z, hv.z, a0.z); a0.w = fmaf(w0.w, hv.w, a0.w);
            c0.x = fmaf(w1.x, hv.x, c0.x); c0.y = fmaf(w1.y, hv.y, c0.y);
            c0.z = fmaf(w1.z, hv.z, c0.z); c0.w = fmaf(w1.w, hv.w, c0.w);
            hv = h4[1][kq * 8 + i];
            a1.x = fmaf(w0.x, hv.x, a1.x); a1.y = fmaf(w0.y, hv.y, a1.y);
            a1.z = fmaf(w0.z, hv.z, a1.z); a1.w = fmaf(w0.w, hv.w, a1.w);
            c1.x = fmaf(w1.x, hv.x, c1.x); c1.y = fmaf(w1.y, hv.y, c1.y);
            c1.z = fmaf(w1.z, hv.z, c1.z); c1.w = fmaf(w1.w, hv.w, c1.w);
            hv = h4[2][kq * 8 + i];
            a2.x = fmaf(w0.x, hv.x, a2.x); a2.y = fmaf(w0.y, hv.y, a2.y);
            a2.z = fmaf(w0.z, hv.z, a2.z); a2.w = fmaf(w0.w, hv.w, a2.w);
            c2.x = fmaf(w1.x, hv.x, c2.x); c2.y = fmaf(w1.y, hv.y, c2.y);
            c2.z = fmaf(w1.z, hv.z, c2.z); c2.w = fmaf(w1.w, hv.w, c2.w);
            hv = h4[3][kq * 8 + i];
            a3.x = fmaf(w0.x, hv.x, a3.x); a3.y = fmaf(w0.y, hv.y, a3.y);
            a3.z = fmaf(w0.z, hv.z, a3.z); a3.w = fmaf(w0.w, hv.w, a3.w);
            c3.x = fmaf(w1.x, hv.x, c3.x); c3.y = fmaf(w1.y, hv.y, c3.y);
            c3.z = fmaf(w1.z, hv.z, c3.z); c3.w = fmaf(w1.w, hv.w, c3.w);
        }
        // x partials (1 float4 per row per seq), uniform — no divergence
        {
            float4 xv;
            float2 pv;
            xv = xb4[buf][0][kq];
            pv.x = a0.x + a0.y + a0.z + a0.w;
            pv.y = c0.x + c0.y + c0.z + c0.w;
            *(float2*)&P[kq][0][lr0] = pv;
            pv.x = wx0.x * xv.x + wx0.y * xv.y + wx0.z * xv.z + wx0.w * xv.w;
            pv.y = wx1.x * xv.x + wx1.y * xv.y + wx1.z * xv.z + wx1.w * xv.w;
            *(float2*)&Px[kq][0][lr0] = pv;
            xv = xb4[buf][1][kq];
            pv.x = a1.x + a1.y + a1.z + a1.w;
            pv.y = c1.x + c1.y + c1.z + c1.w;
            *(float2*)&P[kq][1][lr0] = pv;
            pv.x = wx0.x * xv.x + wx0.y * xv.y + wx0.z * xv.z + wx0.w * xv.w;
            pv.y = wx1.x * xv.x + wx1.y * xv.y + wx1.z * xv.z + wx1.w * xv.w;
            *(float2*)&Px[kq][1][lr0] = pv;
            xv = xb4[buf][2][kq];
            pv.x = a2.x + a2.y + a2.z + a2.w;
            pv.y = c2.x + c2.y + c2.z + c2.w;
            *(float2*)&P[kq][2][lr0] = pv;
            pv.x = wx0.x * xv.x + wx0.y * xv.y + wx0.z * xv.z + wx0.w * xv.w;
            pv.y = wx1.x * xv.x + wx1.y * xv.y + wx1.z * xv.z + wx1.w * xv.w;
            *(float2*)&Px[kq][2][lr0] = pv;
            xv = xb4[buf][3][kq];
            pv.x = a3.x + a3.y + a3.z + a3.w;
            pv.y = c3.x + c3.y + c3.z + c3.w;
            *(float2*)&P[kq][3][lr0] = pv;
            pv.x = wx0.x * xv.x + wx0.y * xv.y + wx0.z * xv.z + wx0.w * xv.w;
            pv.y = wx1.x * xv.x + wx1.y * xv.y + wx1.z * xv.z + wx1.w * xv.w;
            *(float2*)&Px[kq][3][lr0] = pv;
        }
        __syncthreads();

        // ---- phase 2 (tid<256): gates + publish; (tid>=256): gather + x ----
        if (tid < 256) {
            const int j2 = tid & 63, s = tid >> 6;   // one s per wave
            float hr = 0.f, hz = 0.f, hn_ = 0.f, xr = 0.f, xz = 0.f, xn = 0.f;
            #pragma unroll
            for (int kk = 0; kk < 8; ++kk) {
                hr  += P [kk][s][j2];
                hz  += P [kk][s][64 + j2];
                hn_ += P [kk][s][128 + j2];
                xr  += Px[kk][s][j2];
                xz  += Px[kk][s][64 + j2];
                xn  += Px[kk][s][128 + j2];
            }
            const float r = sigmoidf_(xr + bxr + hr + bhr);
            const float z = sigmoidf_(xz + bxz + hz + bhz);
            const float n = tanhf(xn + bxn + r * (hn_ + bhn));
            const int jg = w * 64 + j2;
            const float hp = ((const float*)h4)[s * 256 + jg];
            const float hnew = (1.0f - z) * n + z * hp;
            ((float*)h4)[s * 256 + jg] = hnew;
            union { float f; unsigned ui; } cv; cv.f = hnew;
            const unsigned long long pk =
                ((unsigned long long)(unsigned)step << 32) | cv.ui;
            __hip_atomic_store(&slab[w * 256 + s * 64 + j2], pk,
                               __ATOMIC_RELAXED, __HIP_MEMORY_SCOPE_AGENT);
            if (step == lsS[s]) ze[bbS[s] * D + dir * H + jg] = hnew;
        } else {
            // x prefetch (issue early; completes during spins)
            float xval = 0.0f;
            int xs = 0, xi = 0;
            const bool do_x = (u < 128) && (step < L);
            if (do_x) {
                xs = u >> 5; xi = u & 31;
                const int tn = dir ? (T - 1 - step) : step;
                xval = traj[(bbS[xs] * T + tn) * IN + xi];
            }
            const int p0 = u >> 8;               // peer-list index 0,1
            const int r2 = u & 255;
            const int s0 = r2 >> 6, j0 = r2 & 63;
            const int pw0 = p0 + (p0 >= w ? 1 : 0);
            unsigned long long* ad0 = &slab[pw0 * 256 + s0 * 64 + j0];
            if (u < 256) {
                const int pw1 = 2 + (2 >= w ? 1 : 0);
                unsigned long long* ad1 = &slab[pw1 * 256 + s0 * 64 + j0];
                unsigned long long v0 = 0, v1 = 0;
                bool d0 = false, d1 = false;
                do {   // concurrent double-poll: both loads in flight
                    if (!d0) { v0 = __hip_atomic_load(ad0, __ATOMIC_RELAXED,
                                   __HIP_MEMORY_SCOPE_AGENT); d0 = ((int)(v0 >> 32) >= step); }
                    if (!d1) { v1 = __hip_atomic_load(ad1, __ATOMIC_RELAXED,
                                   __HIP_MEMORY_SCOPE_AGENT); d1 = ((int)(v1 >> 32) >= step); }
                } while (!(d0 && d1));
                union { unsigned ui; float f; } e0, e1;
                e0.ui = (unsigned)v0; e1.ui = (unsigned)v1;
                ((float*)h4)[s0 * 256 + pw0 * 64 + j0] = e0.f;
                ((float*)h4)[s0 * 256 + pw1 * 64 + j0] = e1.f;
            } else {
                unsigned long long v0;
                do {
                    v0 = __hip_atomic_load(ad0, __ATOMIC_RELAXED,
                                           __HIP_MEMORY_SCOPE_AGENT);
                } while ((int)(v0 >> 32) < step);
                union { unsigned ui; float f; } e0; e0.ui = (unsigned)v0;
                ((float*)h4)[s0 * 256 + pw0 * 64 + j0] = e0.f;
            }
            if (do_x)
                ((float*)xb4)[(buf ^ 1) * 128 + xs * 32 + xi] = xval;
        }
        __syncthreads();
    }
}

// ---------------------------------------------------------------------------
// VQ: fp64 distance accumulation to match the numpy (fp64) argmin ordering.
// ---------------------------------------------------------------------------

__global__ __launch_bounds__(256) void k_vq(
    const float* __restrict__ ze, const float* __restrict__ cbT,
    const float* __restrict__ cb, const double* __restrict__ cbn2,
    int* __restrict__ counts, double* __restrict__ lsum,
    float* __restrict__ out)
{
    __shared__ float lz[D];
    __shared__ double ds[256];
    __shared__ int cs[256];

    const int b = blockIdx.x;
    const int t = threadIdx.x;

    lz[t]       = ze[b * D + t];
    lz[t + 256] = ze[b * D + 256 + t];
    __syncthreads();

    double best = 1e300;
    int bc = 0;
    for (int m = 0; m < NC / 256; ++m) {
        const int c = m * 256 + t;
        double s2 = 0.0;
        #pragma unroll 4
        for (int k = 0; k < D; ++k)
            s2 += (double)lz[k] * (double)cbT[k * NC + c];
        const double dist = cbn2[c] - 2.0 * s2;
        if (dist < best) { best = dist; bc = c; }
    }
    ds[t] = best; cs[t] = bc;
    __syncthreads();
    for (int s = 128; s > 0; s >>= 1) {
        if (t < s) {
            if (ds[t + s] < ds[t] || (ds[t + s] == ds[t] && cs[t + s] < cs[t])) {
                ds[t] = ds[t + s]; cs[t] = cs[t + s];
            }
        }
        __syncthreads();
    }
    const int idx = cs[0];
    __syncthreads();

    if (t == 0) atomicAdd(&counts[idx], 1);

    double loc = 0.0;
    for (int jj = t; jj < D; jj += 256) {
        const float zev = lz[jj];
        const float zqv = cb[idx * D + jj];
        out[b * D + jj] = zev + (zqv - zev);
        const double df = (double)zqv - (double)zev;
        loc += df * df;
    }
    ds[t] = loc;
    __syncthreads();
    for (int s = 128; s > 0; s >>= 1) {
        if (t < s) ds[t] += ds[t + s];
        __syncthreads();
    }
    if (t == 0) atomicAdd(lsum, ds[0]);
}

__global__ void k_final(const int* __restrict__ counts,
                        const double* __restrict__ lsum,
                        float* __restrict__ out)
{
    __shared__ double ds[256];
    const int t = threadIdx.x;
    double s = 0.0;
    for (int c = t; c < NC; c += 256) {
        const double p = (double)counts[c] / (double)B;
        s += p * log(p + 1e-10);
    }
    ds[t] = s;
    __syncthreads();
    for (int r = 128; r > 0; r >>= 1) {
        if (t < r) ds[t] += ds[t + r];
        __syncthreads();
    }
    if (t == 0) {
        out[B * D]     = (float)(lsum[0] * 1.25 / (double)(B * D));
        out[B * D + 1] = (float)exp(-ds[0]);
    }
}

// ---------------------------------------------------------------------------
// launch
// ---------------------------------------------------------------------------

extern "C" void kernel_launch(void* const* d_in, const int* in_sizes, int n_in,
                              void* d_out, int out_size, void* d_ws, size_t ws_size,
                              hipStream_t stream) {
    const float* traj = (const float*)d_in[0];
    const int*   mask = (const int*)d_in[1];
    const float* Wxf  = (const float*)d_in[2];
    const float* Whf  = (const float*)d_in[3];
    const float* bxf  = (const float*)d_in[4];
    const float* bhf  = (const float*)d_in[5];
    const float* Wxb  = (const float*)d_in[6];
    const float* Whb  = (const float*)d_in[7];
    const float* bxb  = (const float*)d_in[8];
    const float* bhb  = (const float*)d_in[9];
    const float* cb   = (const float*)d_in[10];
    float* out = (float*)d_out;

    // workspace layout
    float* ws    = (float*)d_ws;
    float* cbT   = ws;                     // 512*1024 = 524288 floats
    float* zebuf = cbT + 524288;           // 128*512  = 65536
    unsigned long long* hgt =
        (unsigned long long*)(zebuf + 65536);   // 2*64*4*256 u64 = 131072 (1 MB)
    int*   last  = (int*)(hgt + 131072);   // 128
    int*   plan  = last + 128;             // 256
    int*   slen  = plan + 256;             // 256
    int*   glen  = slen + 256;             // 64
    int*   cnts  = glen + 64;              // 1024
    double* cbn2 = (double*)(cnts + 1024 + 4); // 1024 doubles (8B aligned)
    double* lsum = cbn2 + 1024;            // 1 double

    k_zero<<<dim3(4), dim3(256), 0, stream>>>(cnts, lsum);
    k_lengths<<<dim3(B), dim3(64), 0, stream>>>(mask, last);
    k_plan<<<dim3(1), dim3(B), 0, stream>>>(last, plan, slen, glen);

    k_transpose<<<dim3(2048), dim3(256), 0, stream>>>(cbT, cb, NC, D);
    k_cbn2<<<dim3(4), dim3(256), 0, stream>>>(cb, cbn2);

    k_gru<<<dim3(NG * GW), dim3(NTHR), 0, stream>>>(
        traj, Whf, Whb, Wxf, Wxb, bxf, bhf, bxb, bhb,
        plan, slen, glen, hgt, zebuf);

    k_vq<<<dim3(B), dim3(256), 0, stream>>>(zebuf, cbT, cb, cbn2, cnts, lsum, out);
    k_final<<<dim3(1), dim3(256), 0, stream>>>(cnts, lsum, out);
}